// Round 2
// baseline (296.367 us; speedup 1.0000x reference)
//
#include <hip/hip_runtime.h>

#define HW_   (512 * 512)   // pixels per image
#define NIMG  8
#define NC    19            // classes
#define NSP   2048          // superpixels per image
#define TC    20            // target row stride (C+1, last col sliced off)
#define NROWS (NIMG * NSP)  // 16384 target rows
#define BTILE 4096          // pixels per block (4 wave-tiles of 1024)
#define NBLK  512           // 2 blocks/CU, covers all 512 block-tiles
#define NGRP  16            // completion-ticket groups (32 blocks each)
#define GSIZE (NBLK / NGRP)

typedef float vf4 __attribute__((ext_vector_type(4)));
typedef int   vi4 __attribute__((ext_vector_type(4)));

// d_ws layout:
//   [0]    flag (uint)       spmask width: 1 -> 4-byte, 0 -> 1-byte
//   [4]    st   (uint)       super ticket
//   [64]   gt[NGRP] uints, stride 16 (64 B apart -> no same-line RMWs)
//   [1088] pl[NBLK] float    per-block loss partials (contention-free)
//   [3136] pc[NBLK] uint     per-block count partials
//   [5184] bmt[NROWS] uint   per-(image,superpixel) multi-hot bitmask

// ---------------------------------------------------------------------------
// Kernel 1: zero tickets, detect spmask width, build target bitmasks.
// Rows are 80 B (16-B aligned) -> 5 dwordx4 per thread, fully vectorized.
// ---------------------------------------------------------------------------
__global__ __launch_bounds__(256) void prep(
    const float* __restrict__ tgt,
    const unsigned int* __restrict__ spm,
    unsigned int* __restrict__ flag, unsigned int* __restrict__ st,
    unsigned int* __restrict__ gt, unsigned int* __restrict__ bm) {

    int gid = blockIdx.x * 256 + threadIdx.x;   // 64 blocks -> 16384 threads
    if (gid == 0) *st = 0u;
    if (gid < NGRP) gt[gid * 16] = 0u;

    if (blockIdx.x == 1 && threadIdx.x < 64) {  // one wave: width detection
        unsigned int nonlow = 0, upper = 0;
        for (int i = threadIdx.x; i < 1024; i += 64) {
            unsigned int v = spm[i];
            nonlow |= (v & 0xFEFEFEFEu);
            upper  |= (v & 0xFFFFFF00u);
        }
        unsigned long long b1 = __ballot(nonlow != 0);
        unsigned long long b2 = __ballot(upper != 0);
        if (threadIdx.x == 0)
            *flag = ((b1 == 0ull) && (b2 != 0ull)) ? 0u : 1u;
    }

    const vf4* row = (const vf4*)(tgt + (size_t)gid * TC);  // 80 B, 16-aligned
    vf4 r0 = row[0], r1 = row[1], r2 = row[2], r3 = row[3], r4 = row[4];
    unsigned int m = 0;
    m |= (r0.x != 0.0f ? 1u : 0u) << 0;  m |= (r0.y != 0.0f ? 1u : 0u) << 1;
    m |= (r0.z != 0.0f ? 1u : 0u) << 2;  m |= (r0.w != 0.0f ? 1u : 0u) << 3;
    m |= (r1.x != 0.0f ? 1u : 0u) << 4;  m |= (r1.y != 0.0f ? 1u : 0u) << 5;
    m |= (r1.z != 0.0f ? 1u : 0u) << 6;  m |= (r1.w != 0.0f ? 1u : 0u) << 7;
    m |= (r2.x != 0.0f ? 1u : 0u) << 8;  m |= (r2.y != 0.0f ? 1u : 0u) << 9;
    m |= (r2.z != 0.0f ? 1u : 0u) << 10; m |= (r2.w != 0.0f ? 1u : 0u) << 11;
    m |= (r3.x != 0.0f ? 1u : 0u) << 12; m |= (r3.y != 0.0f ? 1u : 0u) << 13;
    m |= (r3.z != 0.0f ? 1u : 0u) << 14; m |= (r3.w != 0.0f ? 1u : 0u) << 15;
    m |= (r4.x != 0.0f ? 1u : 0u) << 16; m |= (r4.y != 0.0f ? 1u : 0u) << 17;
    m |= (r4.z != 0.0f ? 1u : 0u) << 18;              // r4.w = col 19, sliced off
    bm[gid] = m;
}

// ---------------------------------------------------------------------------
// Kernel 2: page-run-ordered, class-streamed fused exp-sum + gather + NLL.
// 512 blocks x 256 threads, one 4096-px block-tile each. Each WAVE owns a
// 1024-px tile (16 px/lane as [j=0..3][k=0..3]); per class it issues 4
// consecutive dwordx4 from ONE 4-KB page (vs the old burst's 20-distinct-
// page round-robin that thrashed per-CU address translation on every
// instruction). Classes stream through a 2-deep A/B register pipeline so
// ~8 loads stay in flight with no vmcnt(0) stops. The per-image bitmask
// table (8 KB) is LDS-staged once per block; per-pixel bitmask lookups are
// ds_read (off the vmem pipe) instead of 64-way-divergent global gathers.
// Chip vmem instructions: 204.8k -> ~59k, in same-page runs of 4.
// ---------------------------------------------------------------------------
__global__ __launch_bounds__(256, 2) void mcce_main(
    const float* __restrict__ x,      // (N, C, H*W)
    const int*   __restrict__ sp,     // (N, H*W)
    const void*  __restrict__ spm,    // (N, H*W) mask, 1B or 4B elements
    const unsigned int* __restrict__ bmt,   // (N*NSP) bitmasks
    const unsigned int* __restrict__ flag,
    float* __restrict__ pl, unsigned int* __restrict__ pc,
    unsigned int* __restrict__ st, unsigned int* __restrict__ gt,
    float* __restrict__ out) {

    __shared__ unsigned int bmtab[NSP];     // 8 KB: this image's bitmasks
    __shared__ float sL[4];
    __shared__ unsigned int sC[4];

    int b    = blockIdx.x;
    int t    = threadIdx.x;
    int wave = t >> 6;
    int lane = t & 63;
    // Co-resident blocks (b, b+256) -> adjacent block-tiles of the SAME image.
    int swz  = ((b & 255) << 1) | (b >> 8);
    int n    = swz >> 6;                    // 64 block-tiles per image
    int tp   = (swz & 63) * BTILE;          // base pixel within image
    unsigned int flagv = *flag;             // hoisted; wave-uniform

    // ---- stage this image's bitmask table into LDS (8 coalesced loads) ----
    const unsigned int* bt = bmt + (size_t)n * NSP;
    ((vi4*)bmtab)[t]       = ((const vi4*)bt)[t];
    ((vi4*)bmtab)[t + 256] = ((const vi4*)bt)[t + 256];

    // ---- per-wave tile: sp + spm (issued before the barrier drains) ----
    int wp = tp + wave * 1024;              // wave-tile base pixel
    const int* spw = sp + (size_t)n * HW_ + wp;
    vi4 s4[4];
#pragma unroll
    for (int j = 0; j < 4; ++j)
        s4[j] = ((const vi4*)spw)[lane + j * 64];

    int mkb[4];                             // 4-bit valid-mask per j-group
    size_t mbase = (size_t)n * HW_ + wp;
    if (flagv) {
#pragma unroll
        for (int j = 0; j < 4; ++j) {
            vi4 m = *(const vi4*)((const int*)spm + mbase + j * 256 + lane * 4);
            mkb[j] = (m.x != 0 ? 1 : 0) | (m.y != 0 ? 2 : 0) |
                     (m.z != 0 ? 4 : 0) | (m.w != 0 ? 8 : 0);
        }
    } else {
#pragma unroll
        for (int j = 0; j < 4; ++j) {
            unsigned int mw = *(const unsigned int*)
                              ((const unsigned char*)spm + mbase + j * 256 + lane * 4);
            mkb[j] = ((mw       & 0xFFu) ? 1 : 0) | (((mw >> 8)  & 0xFFu) ? 2 : 0) |
                     (((mw >> 16) & 0xFFu) ? 4 : 0) | (((mw >> 24) & 0xFFu) ? 8 : 0);
        }
    }

    __syncthreads();                        // bmtab ready (drains stage loads)

    // ---- per-pixel bitmasks from LDS (random addr ~2-way conflicts, free) ----
    unsigned int bv[4][4];
#pragma unroll
    for (int j = 0; j < 4; ++j) {
        bv[j][0] = bmtab[s4[j].x]; bv[j][1] = bmtab[s4[j].y];
        bv[j][2] = bmtab[s4[j].z]; bv[j][3] = bmtab[s4[j].w];
    }

    // ---- class-streamed exp-sums, 2-deep A/B pipeline ----
    const float* xw = x + (size_t)n * NC * HW_ + wp;   // class-0 base, this wave
    vf4 A[4], B[4];
    vf4 se[4] = {{0,0,0,0},{0,0,0,0},{0,0,0,0},{0,0,0,0}};
    vf4 ts[4] = {{0,0,0,0},{0,0,0,0},{0,0,0,0},{0,0,0,0}};

#define LDC(R, c) { const vf4* p_ = (const vf4*)(xw + (size_t)(c) * HW_);      \
    _Pragma("unroll") for (int j_ = 0; j_ < 4; ++j_) R[j_] = p_[lane + j_*64]; }

#define PRC(R, c) { _Pragma("unroll") for (int j_ = 0; j_ < 4; ++j_) {         \
    vf4 e_;                                                                    \
    e_.x = __expf(R[j_].x); e_.y = __expf(R[j_].y);                            \
    e_.z = __expf(R[j_].z); e_.w = __expf(R[j_].w);                            \
    se[j_].x += e_.x; se[j_].y += e_.y; se[j_].z += e_.z; se[j_].w += e_.w;    \
    ts[j_].x += ((bv[j_][0] >> (c)) & 1) ? e_.x : 0.0f;                        \
    ts[j_].y += ((bv[j_][1] >> (c)) & 1) ? e_.y : 0.0f;                        \
    ts[j_].z += ((bv[j_][2] >> (c)) & 1) ? e_.z : 0.0f;                        \
    ts[j_].w += ((bv[j_][3] >> (c)) & 1) ? e_.w : 0.0f; } }

    LDC(A, 0)
#pragma unroll
    for (int p = 0; p < 9; ++p) {           // classes 2p, 2p+1; preload 2p+2
        LDC(B, 2 * p + 1)
        PRC(A, 2 * p)
        LDC(A, 2 * p + 2)                   // p=8 -> class 18
        PRC(B, 2 * p + 1)
    }
    PRC(A, 18)

#undef LDC
#undef PRC

    // ---- per-lane NLL over 16 pixels ----
    float lsum = 0.0f;
    unsigned int lcnt = 0;
#pragma unroll
    for (int j = 0; j < 4; ++j) {
        if ((mkb[j] & 1) && bv[j][0]) { lsum -= __logf(ts[j].x / se[j].x + 1e-8f); ++lcnt; }
        if ((mkb[j] & 2) && bv[j][1]) { lsum -= __logf(ts[j].y / se[j].y + 1e-8f); ++lcnt; }
        if ((mkb[j] & 4) && bv[j][2]) { lsum -= __logf(ts[j].z / se[j].z + 1e-8f); ++lcnt; }
        if ((mkb[j] & 8) && bv[j][3]) { lsum -= __logf(ts[j].w / se[j].w + 1e-8f); ++lcnt; }
    }

    // ---- wave-64 shuffle reduction -> LDS block reduction ----
    for (int o = 32; o > 0; o >>= 1) {
        lsum += __shfl_down(lsum, o);
        lcnt += __shfl_down(lcnt, o);
    }
    __syncthreads();                        // bmtab no longer needed; reuse sL/sC
    if ((t & 63) == 0) { sL[wave] = lsum; sC[wave] = lcnt; }
    __syncthreads();

    if (t == 0) {
        float        L = sL[0] + sL[1] + sL[2] + sL[3];
        unsigned int C = sC[0] + sC[1] + sC[2] + sC[3];
        __hip_atomic_store(&pl[b], L, __ATOMIC_RELAXED, __HIP_MEMORY_SCOPE_AGENT);
        __hip_atomic_store(&pc[b], C, __ATOMIC_RELAXED, __HIP_MEMORY_SCOPE_AGENT);
        // Hierarchical tickets: 16 groups of 32 (64-B-padded lines), then
        // one super ticket -> max ~32 same-line RMWs anywhere.
        unsigned int g = (unsigned int)b / GSIZE;
        unsigned int isLast = 0u;
        unsigned int tk = __hip_atomic_fetch_add(&gt[g * 16], 1u,
                              __ATOMIC_ACQ_REL, __HIP_MEMORY_SCOPE_AGENT);
        if (tk == (unsigned int)(GSIZE - 1)) {
            unsigned int s = __hip_atomic_fetch_add(st, 1u,
                                 __ATOMIC_ACQ_REL, __HIP_MEMORY_SCOPE_AGENT);
            isLast = (s == NGRP - 1) ? 1u : 0u;
        }
        sC[0] = isLast;                     // reuse LDS as broadcast
    }
    __syncthreads();

    // Last block: reduce the 512 partials and write the scalar.
    if (sC[0]) {
        float        L = 0.0f;
        unsigned int C = 0u;
        for (int i = t; i < NBLK; i += 256) {
            L += __hip_atomic_load(&pl[i], __ATOMIC_RELAXED, __HIP_MEMORY_SCOPE_AGENT);
            C += __hip_atomic_load(&pc[i], __ATOMIC_RELAXED, __HIP_MEMORY_SCOPE_AGENT);
        }
        for (int o = 32; o > 0; o >>= 1) {
            L += __shfl_down(L, o);
            C += __shfl_down(C, o);
        }
        __syncthreads();                    // LDS reuse barrier
        if ((t & 63) == 0) { sL[wave] = L; sC[wave] = C; }
        __syncthreads();
        if (t == 0) {
            L = sL[0] + sL[1] + sL[2] + sL[3];
            C = sC[0] + sC[1] + sC[2] + sC[3];
            out[0] = L / (float)(1u + C);
        }
    }
}

extern "C" void kernel_launch(void* const* d_in, const int* in_sizes, int n_in,
                              void* d_out, int out_size, void* d_ws, size_t ws_size,
                              hipStream_t stream) {
    const float* x   = (const float*)d_in[0];   // inputs (8,19,512,512) f32
    const float* tgt = (const float*)d_in[1];   // targets (8,2048,20) f32
    const int*   sp  = (const int*)d_in[2];     // superpixels (8,512,512) i32
    const void*  spm = d_in[3];                 // spmasks (8,512,512), width detected

    unsigned int* flag = (unsigned int*)d_ws;
    unsigned int* st   = (unsigned int*)((char*)d_ws + 4);
    unsigned int* gt   = (unsigned int*)((char*)d_ws + 64);
    float*        pl   = (float*)((char*)d_ws + 1088);
    unsigned int* pc   = (unsigned int*)((char*)d_ws + 3136);
    unsigned int* bmt  = (unsigned int*)((char*)d_ws + 5184);

    prep<<<NROWS / 256, 256, 0, stream>>>(tgt, (const unsigned int*)spm,
                                          flag, st, gt, bmt);

    mcce_main<<<NBLK, 256, 0, stream>>>(x, sp, spm, bmt, flag,
                                        pl, pc, st, gt, (float*)d_out);
}